// Round 11
// baseline (881.911 us; speedup 1.0000x reference)
//
#include <hip/hip_runtime.h>
#include <hip/hip_bf16.h>

#define TSTEPS 300
#define INDIM  38
#define NB     8

typedef __attribute__((ext_vector_type(4))) float    float4_;
typedef __attribute__((ext_vector_type(2))) float    float2_;
typedef __attribute__((ext_vector_type(8))) short    short8;
typedef unsigned short ushort_;

__device__ __forceinline__ float frcp(float x){ return __builtin_amdgcn_rcpf(x); }
__device__ __forceinline__ float fexp2(float x){ float r; asm("v_exp_f32 %0, %1" : "=v"(r) : "v"(x)); return r; }
__device__ __forceinline__ float fsig(float x){ return frcp(1.0f + fexp2(-1.44269504f*x)); }
__device__ __forceinline__ float ftanh(float x){ return 1.0f - 2.0f*frcp(1.0f + fexp2(2.88539008f*x)); }
__device__ __forceinline__ unsigned bf16rne(float f){
    unsigned u = __float_as_uint(f);
    return (u + 0x7FFFu + ((u>>16)&1u)) >> 16;
}
// frag-native position of k-element rel (0..31) within a 32-k tile
__device__ __forceinline__ int posk(int rel){ return 8*((rel&15)>>2) + (rel&3) + 4*(rel>>4); }
__device__ __forceinline__ short8 ldf(const ushort_* p){ return *(const short8*)p; }
__device__ __forceinline__ float4_ bmfma(short8 a, short8 b, float4_ c){
    return __builtin_amdgcn_mfma_f32_16x16x32_bf16(a, b, c, 0, 0, 0);
}
// raw barrier: drains LDS only; global loads stay in flight
#define BAR() do{ asm volatile("s_waitcnt lgkmcnt(0)" ::: "memory"); \
                  __builtin_amdgcn_s_barrier(); \
                  asm volatile("" ::: "memory"); }while(0)

// 256 threads = 4 waves, NB=8, one dir per block, grid (256,2)=512 blocks = 2 blocks/CU.
// launch_bounds(256,2): 8 waves/CU packing, 256-reg cap (no spills).
// Wave roles (short chains, no merged roles):
//   wv 0,1: L1 gate-closed tiles {wv,wv+2,wv+4,wv+6}: 36 MFMA -> 4 gates/cell in-lane
//           -> cell1 IN-REGISTER (no gate LDS roundtrip) -> h1 hi/lo -> inH[p&1]
//   wv 2,3: L2 self-contained for 4 batches each: 30 MFMA -> wave-private z2s ->
//           cell2 -> h2 -> h2A[p&1]; plus x staging (pairs) -> inX[(p+1)&1]
// ONE barrier per phase; all cross-wave edges are parity double-buffered:
//   inH: W cell1@p -> R (L1+L2)@p+1 ; inX: W stage@p -> R L1@p+1 ; h2A: W cell2@p -> R L2@p+1
__global__ __launch_bounds__(256,2) void rnn_kernel(
    const float* __restrict__ x,
    const float* __restrict__ Wf1, const float* __restrict__ bf1,
    const float* __restrict__ Wf2, const float* __restrict__ bf2,
    const float* __restrict__ Wb1, const float* __restrict__ bb1,
    const float* __restrict__ Wb2, const float* __restrict__ bb2,
    float* __restrict__ featws)
{
    __shared__ __attribute__((aligned(16))) ushort_ inHh[2][16][40],  inHl[2][16][40];
    __shared__ __attribute__((aligned(16))) ushort_ inXh[2][16][104], inXl[2][16][104];
    __shared__ __attribute__((aligned(16))) ushort_ h2Ah[2][16][40],  h2Al[2][16][40];
    __shared__ float z2s[8][84];

    const int tid = threadIdx.x;
    const int dir = blockIdx.y;
    const int b0  = blockIdx.x * NB;

    const float* W1s = dir ? Wb1 : Wf1;
    const float* b1s = dir ? bb1 : bf1;
    const float* W2s = dir ? Wb2 : Wf2;
    const float* b2s = dir ? bb2 : bf2;

    // ---------------- zero-init (rows 8..15 must stay 0; h1(-1)=h2(-1)=0) ----------------
    for (int i = tid; i < 2*16*40; i += 256){ ((ushort_*)inHh)[i]=0; ((ushort_*)inHl)[i]=0;
                                              ((ushort_*)h2Ah)[i]=0; ((ushort_*)h2Al)[i]=0; }
    for (int i = tid; i < 2*16*104; i += 256){ ((ushort_*)inXh)[i]=0; ((ushort_*)inXl)[i]=0; }
    __syncthreads();
    // ---------------- x(0) -> inX[0] rows 0..7 ----------------
    for (int idx = tid; idx < NB*INDIM; idx += 256){
        int t0 = dir ? (TSTEPS-1) : 0;
        int b = idx / INDIM, k = idx % INDIM;
        int off = (k>>5)*32 + posk(k&31);
        float w = x[((size_t)(b0+b)*TSTEPS + t0)*INDIM + k];
        unsigned hu = bf16rne(w);
        inXh[0][b][off] = (ushort_)hu;
        inXl[0][b][off] = (ushort_)bf16rne(w - __uint_as_float(hu<<16));
    }

    const int wv = tid >> 6;
    const int ln = tid & 63;
    const int g  = ln >> 4;
    const int cl = ln & 15;
    const int g8 = 8*g;
    const int dstep = dir ? -INDIM : INDIM;

    // ================= role state =================
    // ---- L1 (wv 0,1): gate-closed tiles {wv, wv+2, wv+4, wv+6} ----
    short8 B1h[4][3], B1l[4][3];
    float bi1=0.f, bj1=0.f, bf1v=0.f, bo1=0.f;
    int pc1 = 0;
    float c1[4] = {0.f,0.f,0.f,0.f};
    // ---- L2 (wv 2,3): all 5 col-tiles; own batches 4(wv-2)..4(wv-2)+3 ----
    short8 B2h[5][2], B2l[5][2];
    float bz2[5] = {0,0,0,0,0};
    bool zmask = false;
    bool c2v[2] = {false,false}; int c2r[2]={0,0}, c2c[2]={0,0}, c2p[2]={0,0};
    float c2st[2] = {0.f,0.f};
    bool stv[2] = {false,false}; int stb[2]={0,0}, stoff[2]={0,0};
    const float* stp[2] = {x,x}; float2_ xr[2] = {{0,0},{0,0}};

    if (wv < 2){
        #pragma unroll
        for (int q = 0; q < 4; ++q){
            const int t = wv + 2*q;
            #pragma unroll
            for (int kt = 0; kt < 3; ++kt){
                union { short8 s; ushort_ u[8]; } H, L;
                #pragma unroll
                for (int j = 0; j < 8; ++j){
                    int kp = kt*32 + ((j<4) ? (4*g+j) : (16+4*g+j-4));
                    float w = 0.f;
                    if (kp < 70){
                        int row = (kp < 32) ? (38+kp) : (kp-32);  // [h1 | x] order
                        w = W1s[row*128 + 16*t + cl];
                    }
                    unsigned hu = bf16rne(w);
                    H.u[j] = (ushort_)hu;
                    L.u[j] = (ushort_)bf16rne(w - __uint_as_float(hu<<16));
                }
                B1h[q][kt] = H.s; B1l[q][kt] = L.s;
            }
        }
        const int c = 16*wv + cl;          // this lane's cell (0..31)
        pc1 = posk(c);
        bi1 = b1s[c]; bj1 = b1s[c+32]; bf1v = b1s[c+64] + 1.0f; bo1 = b1s[c+96];
    } else {
        #pragma unroll
        for (int t = 0; t < 5; ++t){
            #pragma unroll
            for (int kt = 0; kt < 2; ++kt){
                union { short8 s; ushort_ u[8]; } H, L;
                #pragma unroll
                for (int j = 0; j < 8; ++j){
                    int kp = kt*32 + ((j<4) ? (4*g+j) : (16+4*g+j-4));
                    float w = 0.f;
                    if (kp < 52) w = W2s[kp*80 + 16*t + cl];   // rows [h1(32) | h2(20)]
                    unsigned hu = bf16rne(w);
                    H.u[j] = (ushort_)hu;
                    L.u[j] = (ushort_)bf16rne(w - __uint_as_float(hu<<16));
                }
                B2h[t][kt] = H.s; B2l[t][kt] = L.s;
            }
            int col = 16*t + cl;           // segs of 20: i|j|f|o
            bz2[t] = b2s[col] + ((col/20)==2 ? 1.f : 0.f);
        }
        zmask = (wv==2) ? (g==0) : (g==1);   // wave2 writes rows 0-3, wave3 rows 4-7
        #pragma unroll
        for (int m = 0; m < 2; ++m){
            int e = ln + 64*m; c2v[m] = (e < 80);
            int es = c2v[m] ? e : 0;
            c2r[m] = 4*(wv-2) + es/20; c2c[m] = es%20; c2p[m] = posk(es%20);
        }
        const int sid = (wv-2)*64 + ln;
        int t1 = dir ? (TSTEPS-2) : 1;
        #pragma unroll
        for (int m = 0; m < 2; ++m){
            int e = sid + 128*m; stv[m] = (e < NB*19);
            int es = stv[m] ? e : 0;
            int b = es / 19, k = 2*(es % 19);
            stb[m] = b; stoff[m] = (k>>5)*32 + posk(k&31);
            stp[m] = x + ((size_t)(b0+b)*TSTEPS + t1)*INDIM + k;
            if (stv[m]){ xr[m] = *(const float2_*)stp[m]; stp[m] += dstep; } // preload x(1)
        }
    }
    __syncthreads();   // x(0) staged, roles ready

    // ================= phase body (PX = p&1, literal per call site) =================
    auto phase = [&](int p, int PX){
        const int PR = PX ^ 1;
        if (wv < 2){
            if (p < TSTEPS){
                short8 Ah[3], Al[3];
                Ah[0] = ldf(&inHh[PR][cl][g8]);      Al[0] = ldf(&inHl[PR][cl][g8]);
                Ah[1] = ldf(&inXh[PX][cl][g8]);      Al[1] = ldf(&inXl[PX][cl][g8]);
                Ah[2] = ldf(&inXh[PX][cl][32+g8]);   Al[2] = ldf(&inXl[PX][cl][32+g8]);
                float4_ a0{bi1,bi1,bi1,bi1}, a1{bj1,bj1,bj1,bj1};
                float4_ a2{bf1v,bf1v,bf1v,bf1v}, a3{bo1,bo1,bo1,bo1};
                #pragma unroll
                for (int kt = 0; kt < 3; ++kt){
                    a0 = bmfma(Ah[kt], B1h[0][kt], a0);
                    a1 = bmfma(Ah[kt], B1h[1][kt], a1);
                    a2 = bmfma(Ah[kt], B1h[2][kt], a2);
                    a3 = bmfma(Ah[kt], B1h[3][kt], a3);
                }
                #pragma unroll
                for (int kt = 0; kt < 3; ++kt){
                    a0 = bmfma(Ah[kt], B1l[0][kt], a0);
                    a1 = bmfma(Ah[kt], B1l[1][kt], a1);
                    a2 = bmfma(Ah[kt], B1l[2][kt], a2);
                    a3 = bmfma(Ah[kt], B1l[3][kt], a3);
                }
                #pragma unroll
                for (int kt = 0; kt < 3; ++kt){
                    a0 = bmfma(Al[kt], B1h[0][kt], a0);
                    a1 = bmfma(Al[kt], B1h[1][kt], a1);
                    a2 = bmfma(Al[kt], B1h[2][kt], a2);
                    a3 = bmfma(Al[kt], B1h[3][kt], a3);
                }
                // in-register cell1: batches 4g+r
                #pragma unroll
                for (int r = 0; r < 4; ++r){
                    float si = fsig(a0[r]);
                    float tj = ftanh(a1[r]);
                    float sf = fsig(a2[r]);
                    float so = fsig(a3[r]);
                    c1[r] = fmaf(c1[r], sf, si*tj);
                    float h = ftanh(c1[r]) * so;
                    unsigned hu = bf16rne(h);
                    inHh[PX][4*g+r][pc1] = (ushort_)hu;
                    inHl[PX][4*g+r][pc1] = (ushort_)bf16rne(h - __uint_as_float(hu<<16));
                }
            }
        } else {
            // stage x(p+1) from regs, then issue loads x(p+2)
            if (p <= TSTEPS-2){
                #pragma unroll
                for (int m = 0; m < 2; ++m) if (stv[m]){
                    unsigned h0 = bf16rne(xr[m].x);
                    unsigned l0 = bf16rne(xr[m].x - __uint_as_float(h0<<16));
                    unsigned h1v = bf16rne(xr[m].y);
                    unsigned l1v = bf16rne(xr[m].y - __uint_as_float(h1v<<16));
                    *(unsigned*)&inXh[PR][stb[m]][stoff[m]] = h0 | (h1v<<16);
                    *(unsigned*)&inXl[PR][stb[m]][stoff[m]] = l0 | (l1v<<16);
                }
            }
            if (p <= TSTEPS-3){
                #pragma unroll
                for (int m = 0; m < 2; ++m) if (stv[m]){ xr[m] = *(const float2_*)stp[m]; stp[m] += dstep; }
            }
            if (p >= 1){
                short8 Ah0 = ldf(&inHh[PR][cl][g8]), Al0 = ldf(&inHl[PR][cl][g8]); // h1(p-1)
                short8 Gh  = ldf(&h2Ah[PR][cl][g8]), Gl  = ldf(&h2Al[PR][cl][g8]); // h2(p-2)
                float4_ a[5];
                #pragma unroll
                for (int t = 0; t < 5; ++t) a[t] = float4_{bz2[t],bz2[t],bz2[t],bz2[t]};
                #pragma unroll
                for (int t = 0; t < 5; ++t) a[t] = bmfma(Ah0, B2h[t][0], a[t]);
                #pragma unroll
                for (int t = 0; t < 5; ++t) a[t] = bmfma(Gh,  B2h[t][1], a[t]);
                #pragma unroll
                for (int t = 0; t < 5; ++t) a[t] = bmfma(Ah0, B2l[t][0], a[t]);
                #pragma unroll
                for (int t = 0; t < 5; ++t) a[t] = bmfma(Gh,  B2l[t][1], a[t]);
                #pragma unroll
                for (int t = 0; t < 5; ++t) a[t] = bmfma(Al0, B2h[t][0], a[t]);
                #pragma unroll
                for (int t = 0; t < 5; ++t) a[t] = bmfma(Gl,  B2h[t][1], a[t]);
                if (zmask){
                    #pragma unroll
                    for (int t = 0; t < 5; ++t){
                        #pragma unroll
                        for (int r = 0; r < 4; ++r) z2s[4*g + r][16*t + cl] = a[t][r];
                    }
                }
                // cell2 (wave-private z2s rows; compiler orders via lgkmcnt)
                #pragma unroll
                for (int m = 0; m < 2; ++m) if (c2v[m]){
                    const int rw = c2r[m], c = c2c[m];
                    float zi = z2s[rw][c],    zj = z2s[rw][c+20];
                    float zf = z2s[rw][c+40], zo = z2s[rw][c+60];
                    c2st[m] = fmaf(c2st[m], fsig(zf), fsig(zi)*ftanh(zj));
                    float h = ftanh(c2st[m]) * fsig(zo);
                    unsigned hu = bf16rne(h);
                    h2Ah[PX][rw][c2p[m]] = (ushort_)hu;
                    h2Al[PX][rw][c2p[m]] = (ushort_)bf16rne(h - __uint_as_float(hu<<16));
                    if (p == 1 || p == TSTEPS){
                        int off = (p == 1) ? (dir ? 60 : 0) : (dir ? 20 : 40);
                        featws[(size_t)(b0+rw)*80 + off + c] = h;
                    }
                }
            }
        }
        BAR();
    };

    for (int pp = 0; pp < TSTEPS; pp += 2){
        phase(pp, 0);
        phase(pp+1, 1);
    }
    phase(TSTEPS, 0);   // p=300: L2 finishes h2(299) (+featws); L1 idle
}

__global__ __launch_bounds__(64) void fc_kernel(
    const float* __restrict__ featws,
    const float* __restrict__ Wfc1, const float* __restrict__ bfc1,
    const float* __restrict__ Wfc2, const float* __restrict__ bfc2,
    const float* __restrict__ Wfc3, const float* __restrict__ bfc3,
    float* __restrict__ out)
{
    __shared__ float f[80];
    __shared__ float h1b[80];
    __shared__ float h2b[20];
    const int b = blockIdx.x;
    const int lane = threadIdx.x;

    for (int i = lane; i < 80; i += 64) f[i] = featws[(size_t)b*80 + i];
    __syncthreads();
    for (int j = lane; j < 80; j += 64){
        float s = bfc1[j];
        #pragma unroll 8
        for (int k = 0; k < 80; ++k) s += f[k]*Wfc1[k*80 + j];
        h1b[j] = ftanh(s);
    }
    __syncthreads();
    if (lane < 20){
        float s = bfc2[lane];
        #pragma unroll 8
        for (int k = 0; k < 80; ++k) s += h1b[k]*Wfc2[k*20 + lane];
        h2b[lane] = ftanh(s);
    }
    __syncthreads();
    if (lane < 3){
        float s = bfc3[lane];
        #pragma unroll
        for (int k = 0; k < 20; ++k) s += h2b[k]*Wfc3[k*3 + lane];
        out[(size_t)b*3 + lane] = s;
    }
}

extern "C" void kernel_launch(void* const* d_in, const int* in_sizes, int n_in,
                              void* d_out, int out_size, void* d_ws, size_t ws_size,
                              hipStream_t stream) {
    const float* x    = (const float*)d_in[0];
    const float* Wf1  = (const float*)d_in[1];
    const float* bf1  = (const float*)d_in[2];
    const float* Wf2  = (const float*)d_in[3];
    const float* bf2  = (const float*)d_in[4];
    const float* Wb1  = (const float*)d_in[5];
    const float* bb1  = (const float*)d_in[6];
    const float* Wb2  = (const float*)d_in[7];
    const float* bb2  = (const float*)d_in[8];
    const float* Wfc1 = (const float*)d_in[9];
    const float* bfc1 = (const float*)d_in[10];
    const float* Wfc2 = (const float*)d_in[11];
    const float* bfc2 = (const float*)d_in[12];
    const float* Wfc3 = (const float*)d_in[13];
    const float* bfc3 = (const float*)d_in[14];

    float* feat = (float*)d_ws; // 2048*80*4 = 655360 B

    rnn_kernel<<<dim3(2048/NB, 2), 256, 0, stream>>>(
        x, Wf1, bf1, Wf2, bf2, Wb1, bb1, Wb2, bb2, feat);
    fc_kernel<<<2048, 64, 0, stream>>>(
        feat, Wfc1, bfc1, Wfc2, bfc2, Wfc3, bfc3, (float*)d_out);
}

// Round 12
// 389.133 us; speedup vs baseline: 2.2663x; 2.2663x over previous
//
#include <hip/hip_runtime.h>
#include <hip/hip_bf16.h>

#define TSTEPS 300
#define INDIM  38
#define NB     8

typedef __attribute__((ext_vector_type(4))) float    float4_;
typedef __attribute__((ext_vector_type(2))) float    float2_;
typedef __attribute__((ext_vector_type(8))) short    short8;
typedef unsigned short ushort_;

__device__ __forceinline__ float frcp(float x){ return __builtin_amdgcn_rcpf(x); }
__device__ __forceinline__ float fexp2(float x){ float r; asm("v_exp_f32 %0, %1" : "=v"(r) : "v"(x)); return r; }
__device__ __forceinline__ float fsig(float x){ return frcp(1.0f + fexp2(-1.44269504f*x)); }
__device__ __forceinline__ float ftanh(float x){ return 1.0f - 2.0f*frcp(1.0f + fexp2(2.88539008f*x)); }
__device__ __forceinline__ unsigned bf16rne(float f){
    unsigned u = __float_as_uint(f);
    return (u + 0x7FFFu + ((u>>16)&1u)) >> 16;
}
// frag-native position of k-element rel (0..31) within a 32-k tile
__device__ __forceinline__ int posk(int rel){ return 8*((rel&15)>>2) + (rel&3) + 4*(rel>>4); }
__device__ __forceinline__ short8 ldf(const ushort_* p){ return *(const short8*)p; }
__device__ __forceinline__ float4_ bmfma(short8 a, short8 b, float4_ c){
    return __builtin_amdgcn_mfma_f32_16x16x32_bf16(a, b, c, 0, 0, 0);
}
// raw barrier: drains LDS only; global loads stay in flight
#define BAR() do{ asm volatile("s_waitcnt lgkmcnt(0)" ::: "memory"); \
                  __builtin_amdgcn_s_barrier(); \
                  asm volatile("" ::: "memory"); }while(0)

// 256 threads = 4 waves, NB=8, one dir/block, grid (256,2)=512 blocks = 2 blocks/CU
// ((256,2) hint -> 8 waves/CU packing; VGPR budget 128 arch + 128 acc).
// Register discipline (r11 spilled at 96 weight VGPRs): only HI weight planes in
// registers (L1 48, L2 40 VGPRs); LO planes stay in LDS, streamed per phase.
// Wave roles (short chains):
//  wv 0,1: L1 gate-closed tiles {wv,wv+2,wv+4,wv+6}; cell1 in-register; h1 -> inH[PX]
//  wv 2,3: L2 (redundant MFMA, own 4 batches) -> z2s (wave-private) -> cell2 -> h2A[PX];
//          + x staging -> inX[PR]
// ONE barrier/phase; parity double-buffered inH/inX/h2A (edge table verified r11).
__global__ __launch_bounds__(256,2) void rnn_kernel(
    const float* __restrict__ x,
    const float* __restrict__ Wf1, const float* __restrict__ bf1,
    const float* __restrict__ Wf2, const float* __restrict__ bf2,
    const float* __restrict__ Wb1, const float* __restrict__ bb1,
    const float* __restrict__ Wb2, const float* __restrict__ bb2,
    float* __restrict__ featws)
{
    __shared__ __attribute__((aligned(16))) ushort_ W1Fl[8][16][104];   // lo plane, frag-native
    __shared__ __attribute__((aligned(16))) ushort_ W2Fl[5][16][72];    // lo plane
    __shared__ __attribute__((aligned(16))) ushort_ inHh[2][16][40],  inHl[2][16][40];
    __shared__ __attribute__((aligned(16))) ushort_ inXh[2][16][104], inXl[2][16][104];
    __shared__ __attribute__((aligned(16))) ushort_ h2Ah[2][16][40],  h2Al[2][16][40];
    __shared__ float z2s[8][84];

    const int tid = threadIdx.x;
    const int dir = blockIdx.y;
    const int b0  = blockIdx.x * NB;

    const float* W1s = dir ? Wb1 : Wf1;
    const float* b1s = dir ? bb1 : bf1;
    const float* W2s = dir ? Wb2 : Wf2;
    const float* b2s = dir ? bb2 : bf2;

    // ---------------- zero-init (pads + rows 8..15 + h(-1)=0) ----------------
    for (int i = tid; i < 8*16*104; i += 256) ((ushort_*)W1Fl)[i] = 0;
    for (int i = tid; i < 5*16*72;  i += 256) ((ushort_*)W2Fl)[i] = 0;
    for (int i = tid; i < 2*16*40;  i += 256){ ((ushort_*)inHh)[i]=0; ((ushort_*)inHl)[i]=0;
                                               ((ushort_*)h2Ah)[i]=0; ((ushort_*)h2Al)[i]=0; }
    for (int i = tid; i < 2*16*104; i += 256){ ((ushort_*)inXh)[i]=0; ((ushort_*)inXl)[i]=0; }
    __syncthreads();
    // ---------------- stage weight LO planes (frag-native) ----------------
    for (int idx = tid; idx < 70*128; idx += 256){
        int k = idx >> 7, c = idx & 127;
        int kp = (k < INDIM) ? (k + 32) : (k - INDIM);   // [h1(0..31) | x(32..69)]
        float w = W1s[idx];
        unsigned hu = bf16rne(w);
        W1Fl[c>>4][c&15][(kp>>5)*32 + posk(kp&31)] =
            (ushort_)bf16rne(w - __uint_as_float(hu<<16));
    }
    for (int idx = tid; idx < 52*80; idx += 256){
        int k = idx / 80, c = idx % 80;                  // [h1(0..31) | h2(32..51)]
        float w = W2s[idx];
        unsigned hu = bf16rne(w);
        W2Fl[c/16][c&15][(k>>5)*32 + posk(k&31)] =
            (ushort_)bf16rne(w - __uint_as_float(hu<<16));
    }
    // ---------------- x(0) -> inX[0] rows 0..7 ----------------
    for (int idx = tid; idx < NB*INDIM; idx += 256){
        int t0 = dir ? (TSTEPS-1) : 0;
        int b = idx / INDIM, k = idx % INDIM;
        int off = (k>>5)*32 + posk(k&31);
        float w = x[((size_t)(b0+b)*TSTEPS + t0)*INDIM + k];
        unsigned hu = bf16rne(w);
        inXh[0][b][off] = (ushort_)hu;
        inXl[0][b][off] = (ushort_)bf16rne(w - __uint_as_float(hu<<16));
    }

    const int wv = tid >> 6;
    const int ln = tid & 63;
    const int g  = ln >> 4;
    const int cl = ln & 15;
    const int g8 = 8*g;
    const int dstep = dir ? -INDIM : INDIM;

    // ================= role state =================
    short8 B1h[4][3];                       // L1 hi planes (48 VGPR)
    float bq[4] = {0,0,0,0};
    int pc1 = 0;
    float c1[4] = {0.f,0.f,0.f,0.f};
    short8 B2h[5][2];                       // L2 hi planes (40 VGPR)
    float bz2[5] = {0,0,0,0,0};
    bool zmask = false;
    bool c2v[2] = {false,false}; int c2r[2]={0,0}, c2c[2]={0,0}, c2p[2]={0,0};
    float c2st[2] = {0.f,0.f};
    bool stv[2] = {false,false}; int stb[2]={0,0}, stoff[2]={0,0};
    const float* stp[2] = {x,x}; float2_ xr[2] = {{0,0},{0,0}};

    if (wv < 2){
        #pragma unroll
        for (int q = 0; q < 4; ++q){
            const int t = wv + 2*q;
            #pragma unroll
            for (int kt = 0; kt < 3; ++kt){
                union { short8 s; ushort_ u[8]; } H;
                #pragma unroll
                for (int j = 0; j < 8; ++j){
                    int kp = kt*32 + ((j<4) ? (4*g+j) : (16+4*g+j-4));
                    float w = 0.f;
                    if (kp < 70){
                        int row = (kp < 32) ? (38+kp) : (kp-32);
                        w = W1s[row*128 + 16*t + cl];
                    }
                    H.u[j] = (ushort_)bf16rne(w);
                }
                B1h[q][kt] = H.s;
            }
        }
        const int c = 16*wv + cl;
        pc1 = posk(c);
        bq[0] = b1s[c]; bq[1] = b1s[c+32]; bq[2] = b1s[c+64] + 1.0f; bq[3] = b1s[c+96];
    } else {
        #pragma unroll
        for (int t = 0; t < 5; ++t){
            #pragma unroll
            for (int kt = 0; kt < 2; ++kt){
                union { short8 s; ushort_ u[8]; } H;
                #pragma unroll
                for (int j = 0; j < 8; ++j){
                    int kp = kt*32 + ((j<4) ? (4*g+j) : (16+4*g+j-4));
                    float w = 0.f;
                    if (kp < 52) w = W2s[kp*80 + 16*t + cl];
                    H.u[j] = (ushort_)bf16rne(w);
                }
                B2h[t][kt] = H.s;
            }
            int col = 16*t + cl;
            bz2[t] = b2s[col] + ((col/20)==2 ? 1.f : 0.f);
        }
        zmask = (wv==2) ? (g==0) : (g==1);
        #pragma unroll
        for (int m = 0; m < 2; ++m){
            int e = ln + 64*m; c2v[m] = (e < 80);
            int es = c2v[m] ? e : 0;
            c2r[m] = 4*(wv-2) + es/20; c2c[m] = es%20; c2p[m] = posk(es%20);
        }
        const int sid = (wv-2)*64 + ln;
        int t1 = dir ? (TSTEPS-2) : 1;
        #pragma unroll
        for (int m = 0; m < 2; ++m){
            int e = sid + 128*m; stv[m] = (e < NB*19);
            int es = stv[m] ? e : 0;
            int b = es / 19, k = 2*(es % 19);
            stb[m] = b; stoff[m] = (k>>5)*32 + posk(k&31);
            stp[m] = x + ((size_t)(b0+b)*TSTEPS + t1)*INDIM + k;
            if (stv[m]){ xr[m] = *(const float2_*)stp[m]; stp[m] += dstep; }
        }
    }
    __syncthreads();

    // ================= phase body =================
    auto phase = [&](int p, int PX){
        const int PR = PX ^ 1;
        if (wv < 2){
            if (p < TSTEPS){
                short8 Ah[3], Al[3];
                Ah[0] = ldf(&inHh[PR][cl][g8]);      Al[0] = ldf(&inHl[PR][cl][g8]);
                Ah[1] = ldf(&inXh[PX][cl][g8]);      Al[1] = ldf(&inXl[PX][cl][g8]);
                Ah[2] = ldf(&inXh[PX][cl][32+g8]);   Al[2] = ldf(&inXl[PX][cl][32+g8]);
                // 12 chains of depth 3: hh (bias-init) | hl | lh
                float4_ hh[4], hl[4], lh[4];
                #pragma unroll
                for (int q = 0; q < 4; ++q){
                    hh[q] = float4_{bq[q],bq[q],bq[q],bq[q]};
                    hl[q] = float4_{0,0,0,0};
                    lh[q] = float4_{0,0,0,0};
                }
                #pragma unroll
                for (int kt = 0; kt < 3; ++kt){
                    #pragma unroll
                    for (int q = 0; q < 4; ++q) hh[q] = bmfma(Ah[kt], B1h[q][kt], hh[q]);
                }
                #pragma unroll
                for (int kt = 0; kt < 3; ++kt){
                    #pragma unroll
                    for (int q = 0; q < 4; ++q){
                        short8 bl = ldf(&W1Fl[wv + 2*q][cl][kt*32 + g8]);
                        hl[q] = bmfma(Ah[kt], bl, hl[q]);
                    }
                }
                #pragma unroll
                for (int kt = 0; kt < 3; ++kt){
                    #pragma unroll
                    for (int q = 0; q < 4; ++q) lh[q] = bmfma(Al[kt], B1h[q][kt], lh[q]);
                }
                float4_ a0 = hh[0]+hl[0]+lh[0];
                float4_ a1 = hh[1]+hl[1]+lh[1];
                float4_ a2 = hh[2]+hl[2]+lh[2];
                float4_ a3 = hh[3]+hl[3]+lh[3];
                #pragma unroll
                for (int r = 0; r < 4; ++r){
                    float si = fsig(a0[r]);
                    float tj = ftanh(a1[r]);
                    float sf = fsig(a2[r]);
                    float so = fsig(a3[r]);
                    c1[r] = fmaf(c1[r], sf, si*tj);
                    float h = ftanh(c1[r]) * so;
                    unsigned hu = bf16rne(h);
                    inHh[PX][4*g+r][pc1] = (ushort_)hu;
                    inHl[PX][4*g+r][pc1] = (ushort_)bf16rne(h - __uint_as_float(hu<<16));
                }
            }
        } else {
            if (p <= TSTEPS-2){
                #pragma unroll
                for (int m = 0; m < 2; ++m) if (stv[m]){
                    unsigned h0 = bf16rne(xr[m].x);
                    unsigned l0 = bf16rne(xr[m].x - __uint_as_float(h0<<16));
                    unsigned h1v = bf16rne(xr[m].y);
                    unsigned l1v = bf16rne(xr[m].y - __uint_as_float(h1v<<16));
                    *(unsigned*)&inXh[PR][stb[m]][stoff[m]] = h0 | (h1v<<16);
                    *(unsigned*)&inXl[PR][stb[m]][stoff[m]] = l0 | (l1v<<16);
                }
            }
            if (p <= TSTEPS-3){
                #pragma unroll
                for (int m = 0; m < 2; ++m) if (stv[m]){ xr[m] = *(const float2_*)stp[m]; stp[m] += dstep; }
            }
            if (p >= 1){
                short8 Ah0 = ldf(&inHh[PR][cl][g8]), Al0 = ldf(&inHl[PR][cl][g8]); // h1(p-1)
                short8 Gh  = ldf(&h2Ah[PR][cl][g8]), Gl  = ldf(&h2Al[PR][cl][g8]); // h2(p-2)
                float4_ hh[5], hl[5], lh[5];
                #pragma unroll
                for (int t = 0; t < 5; ++t){
                    hh[t] = float4_{bz2[t],bz2[t],bz2[t],bz2[t]};
                    hl[t] = float4_{0,0,0,0};
                    lh[t] = float4_{0,0,0,0};
                }
                #pragma unroll
                for (int t = 0; t < 5; ++t) hh[t] = bmfma(Ah0, B2h[t][0], hh[t]);
                #pragma unroll
                for (int t = 0; t < 5; ++t) hh[t] = bmfma(Gh,  B2h[t][1], hh[t]);
                #pragma unroll
                for (int t = 0; t < 5; ++t){
                    short8 bl0 = ldf(&W2Fl[t][cl][g8]);
                    hl[t] = bmfma(Ah0, bl0, hl[t]);
                }
                #pragma unroll
                for (int t = 0; t < 5; ++t){
                    short8 bl1 = ldf(&W2Fl[t][cl][32 + g8]);
                    hl[t] = bmfma(Gh, bl1, hl[t]);
                }
                #pragma unroll
                for (int t = 0; t < 5; ++t) lh[t] = bmfma(Al0, B2h[t][0], lh[t]);
                #pragma unroll
                for (int t = 0; t < 5; ++t) lh[t] = bmfma(Gl,  B2h[t][1], lh[t]);
                if (zmask){
                    #pragma unroll
                    for (int t = 0; t < 5; ++t){
                        float4_ a = hh[t] + hl[t] + lh[t];
                        #pragma unroll
                        for (int r = 0; r < 4; ++r) z2s[4*g + r][16*t + cl] = a[r];
                    }
                }
                #pragma unroll
                for (int m = 0; m < 2; ++m) if (c2v[m]){
                    const int rw = c2r[m], c = c2c[m];
                    float zi = z2s[rw][c],    zj = z2s[rw][c+20];
                    float zf = z2s[rw][c+40], zo = z2s[rw][c+60];
                    c2st[m] = fmaf(c2st[m], fsig(zf), fsig(zi)*ftanh(zj));
                    float h = ftanh(c2st[m]) * fsig(zo);
                    unsigned hu = bf16rne(h);
                    h2Ah[PX][rw][c2p[m]] = (ushort_)hu;
                    h2Al[PX][rw][c2p[m]] = (ushort_)bf16rne(h - __uint_as_float(hu<<16));
                    if (p == 1 || p == TSTEPS){
                        int off = (p == 1) ? (dir ? 60 : 0) : (dir ? 20 : 40);
                        featws[(size_t)(b0+rw)*80 + off + c] = h;
                    }
                }
            }
        }
        BAR();
    };

    for (int pp = 0; pp < TSTEPS; pp += 2){
        phase(pp, 0);
        phase(pp+1, 1);
    }
    phase(TSTEPS, 0);   // p=300: finish h2(299) + featws; L1 idle
}

__global__ __launch_bounds__(64) void fc_kernel(
    const float* __restrict__ featws,
    const float* __restrict__ Wfc1, const float* __restrict__ bfc1,
    const float* __restrict__ Wfc2, const float* __restrict__ bfc2,
    const float* __restrict__ Wfc3, const float* __restrict__ bfc3,
    float* __restrict__ out)
{
    __shared__ float f[80];
    __shared__ float h1b[80];
    __shared__ float h2b[20];
    const int b = blockIdx.x;
    const int lane = threadIdx.x;

    for (int i = lane; i < 80; i += 64) f[i] = featws[(size_t)b*80 + i];
    __syncthreads();
    for (int j = lane; j < 80; j += 64){
        float s = bfc1[j];
        #pragma unroll 8
        for (int k = 0; k < 80; ++k) s += f[k]*Wfc1[k*80 + j];
        h1b[j] = ftanh(s);
    }
    __syncthreads();
    if (lane < 20){
        float s = bfc2[lane];
        #pragma unroll 8
        for (int k = 0; k < 80; ++k) s += h1b[k]*Wfc2[k*20 + lane];
        h2b[lane] = ftanh(s);
    }
    __syncthreads();
    if (lane < 3){
        float s = bfc3[lane];
        #pragma unroll
        for (int k = 0; k < 20; ++k) s += h2b[k]*Wfc3[k*3 + lane];
        out[(size_t)b*3 + lane] = s;
    }
}

extern "C" void kernel_launch(void* const* d_in, const int* in_sizes, int n_in,
                              void* d_out, int out_size, void* d_ws, size_t ws_size,
                              hipStream_t stream) {
    const float* x    = (const float*)d_in[0];
    const float* Wf1  = (const float*)d_in[1];
    const float* bf1  = (const float*)d_in[2];
    const float* Wf2  = (const float*)d_in[3];
    const float* bf2  = (const float*)d_in[4];
    const float* Wb1  = (const float*)d_in[5];
    const float* bb1  = (const float*)d_in[6];
    const float* Wb2  = (const float*)d_in[7];
    const float* bb2  = (const float*)d_in[8];
    const float* Wfc1 = (const float*)d_in[9];
    const float* bfc1 = (const float*)d_in[10];
    const float* Wfc2 = (const float*)d_in[11];
    const float* bfc2 = (const float*)d_in[12];
    const float* Wfc3 = (const float*)d_in[13];
    const float* bfc3 = (const float*)d_in[14];

    float* feat = (float*)d_ws; // 2048*80*4 = 655360 B

    rnn_kernel<<<dim3(2048/NB, 2), 256, 0, stream>>>(
        x, Wf1, bf1, Wf2, bf2, Wb1, bb1, Wb2, bb2, feat);
    fc_kernel<<<2048, 64, 0, stream>>>(
        feat, Wfc1, bfc1, Wfc2, bfc2, Wfc3, bfc3, (float*)d_out);
}

// Round 13
// 349.548 us; speedup vs baseline: 2.5230x; 1.1132x over previous
//
#include <hip/hip_runtime.h>
#include <hip/hip_bf16.h>

#define TSTEPS 300
#define INDIM  38
#define NB     8

typedef __attribute__((ext_vector_type(4))) float    float4_;
typedef __attribute__((ext_vector_type(2))) float    float2_;
typedef __attribute__((ext_vector_type(8))) short    short8;
typedef unsigned short ushort_;

__device__ __forceinline__ float frcp(float x){ return __builtin_amdgcn_rcpf(x); }
__device__ __forceinline__ float fexp2(float x){ float r; asm("v_exp_f32 %0, %1" : "=v"(r) : "v"(x)); return r; }
__device__ __forceinline__ float fsig(float x){ return frcp(1.0f + fexp2(-1.44269504f*x)); }
__device__ __forceinline__ float ftanh(float x){ return 1.0f - 2.0f*frcp(1.0f + fexp2(2.88539008f*x)); }
__device__ __forceinline__ unsigned bf16rne(float f){
    unsigned u = __float_as_uint(f);
    return (u + 0x7FFFu + ((u>>16)&1u)) >> 16;
}
// single f32 -> bf16 in low 16 bits (1 inst)
__device__ __forceinline__ unsigned cvt1(float f){
    unsigned r; asm("v_cvt_pk_bf16_f32 %0,%1,%1" : "=v"(r) : "v"(f)); return r;
}
__device__ __forceinline__ unsigned cvt2(float a, float b){
    unsigned r; asm("v_cvt_pk_bf16_f32 %0,%1,%2" : "=v"(r) : "v"(a), "v"(b)); return r;
}
// frag-native position of k-element rel (0..31) within a 32-k tile
__device__ __forceinline__ int posk(int rel){ return 8*((rel&15)>>2) + (rel&3) + 4*(rel>>4); }
__device__ __forceinline__ short8 ldf(const ushort_* p){ return *(const short8*)p; }
__device__ __forceinline__ float4_ bmfma(short8 a, short8 b, float4_ c){
    return __builtin_amdgcn_mfma_f32_16x16x32_bf16(a, b, c, 0, 0, 0);
}
// raw barrier: drains LDS only; global loads stay in flight
#define BAR() do{ asm volatile("s_waitcnt lgkmcnt(0)" ::: "memory"); \
                  __builtin_amdgcn_s_barrier(); \
                  asm volatile("" ::: "memory"); }while(0)

// r12 skeleton (best: 389us): 256 thr = 4 waves, NB=8, grid (256,2)=512 blocks = 2/CU.
// HI weight planes in registers (L1 48, L2 40 VGPR); LO planes streamed from LDS.
// r13 deltas: (a) cell1 redistributed via shfl_xor(32) -> 2 real cells/lane (halves
// L1 transcendentals; upper half-wave was computing garbage rows 8-15);
// (b) v_cvt_pk_bf16_f32 packing; (c) hh+hl merged into one bias-init chain.
__global__ __launch_bounds__(256,2) void rnn_kernel(
    const float* __restrict__ x,
    const float* __restrict__ Wf1, const float* __restrict__ bf1,
    const float* __restrict__ Wf2, const float* __restrict__ bf2,
    const float* __restrict__ Wb1, const float* __restrict__ bb1,
    const float* __restrict__ Wb2, const float* __restrict__ bb2,
    float* __restrict__ featws)
{
    __shared__ __attribute__((aligned(16))) ushort_ W1Fl[8][16][104];   // lo plane, frag-native
    __shared__ __attribute__((aligned(16))) ushort_ W2Fl[5][16][72];    // lo plane
    __shared__ __attribute__((aligned(16))) ushort_ inHh[2][16][40],  inHl[2][16][40];
    __shared__ __attribute__((aligned(16))) ushort_ inXh[2][16][104], inXl[2][16][104];
    __shared__ __attribute__((aligned(16))) ushort_ h2Ah[2][16][40],  h2Al[2][16][40];
    __shared__ float z2s[8][84];

    const int tid = threadIdx.x;
    const int dir = blockIdx.y;
    const int b0  = blockIdx.x * NB;

    const float* W1s = dir ? Wb1 : Wf1;
    const float* b1s = dir ? bb1 : bf1;
    const float* W2s = dir ? Wb2 : Wf2;
    const float* b2s = dir ? bb2 : bf2;

    // ---------------- zero-init (pads + rows 8..15 + h(-1)=0) ----------------
    for (int i = tid; i < 8*16*104; i += 256) ((ushort_*)W1Fl)[i] = 0;
    for (int i = tid; i < 5*16*72;  i += 256) ((ushort_*)W2Fl)[i] = 0;
    for (int i = tid; i < 2*16*40;  i += 256){ ((ushort_*)inHh)[i]=0; ((ushort_*)inHl)[i]=0;
                                               ((ushort_*)h2Ah)[i]=0; ((ushort_*)h2Al)[i]=0; }
    for (int i = tid; i < 2*16*104; i += 256){ ((ushort_*)inXh)[i]=0; ((ushort_*)inXl)[i]=0; }
    __syncthreads();
    // ---------------- stage weight LO planes (frag-native) ----------------
    for (int idx = tid; idx < 70*128; idx += 256){
        int k = idx >> 7, c = idx & 127;
        int kp = (k < INDIM) ? (k + 32) : (k - INDIM);   // [h1(0..31) | x(32..69)]
        float w = W1s[idx];
        unsigned hu = bf16rne(w);
        W1Fl[c>>4][c&15][(kp>>5)*32 + posk(kp&31)] =
            (ushort_)bf16rne(w - __uint_as_float(hu<<16));
    }
    for (int idx = tid; idx < 52*80; idx += 256){
        int k = idx / 80, c = idx % 80;                  // [h1(0..31) | h2(32..51)]
        float w = W2s[idx];
        unsigned hu = bf16rne(w);
        W2Fl[c/16][c&15][(k>>5)*32 + posk(k&31)] =
            (ushort_)bf16rne(w - __uint_as_float(hu<<16));
    }
    // ---------------- x(0) -> inX[0] rows 0..7 ----------------
    for (int idx = tid; idx < NB*INDIM; idx += 256){
        int t0 = dir ? (TSTEPS-1) : 0;
        int b = idx / INDIM, k = idx % INDIM;
        int off = (k>>5)*32 + posk(k&31);
        float w = x[((size_t)(b0+b)*TSTEPS + t0)*INDIM + k];
        unsigned hu = bf16rne(w);
        inXh[0][b][off] = (ushort_)hu;
        inXl[0][b][off] = (ushort_)bf16rne(w - __uint_as_float(hu<<16));
    }

    const int wv = tid >> 6;
    const int ln = tid & 63;
    const int g  = ln >> 4;
    const int cl = ln & 15;
    const int g8 = 8*g;
    const int dstep = dir ? -INDIM : INDIM;

    // ================= role state =================
    short8 B1h[4][3];                       // L1 hi planes (48 VGPR)
    float bq[4] = {0,0,0,0};
    int pc1 = 0, r1row0 = 0, r1row1 = 0;
    float c1a = 0.f, c1b = 0.f;
    short8 B2h[5][2];                       // L2 hi planes (40 VGPR)
    float bz2[5] = {0,0,0,0,0};
    bool zmask = false;
    bool c2v[2] = {false,false}; int c2r[2]={0,0}, c2c[2]={0,0}, c2p[2]={0,0};
    float c2st[2] = {0.f,0.f};
    bool stv[2] = {false,false}; int stb[2]={0,0}, stoff[2]={0,0};
    const float* stp[2] = {x,x}; float2_ xr[2] = {{0,0},{0,0}};

    if (wv < 2){
        #pragma unroll
        for (int q = 0; q < 4; ++q){
            const int t = wv + 2*q;
            #pragma unroll
            for (int kt = 0; kt < 3; ++kt){
                union { short8 s; ushort_ u[8]; } H;
                #pragma unroll
                for (int j = 0; j < 8; ++j){
                    int kp = kt*32 + ((j<4) ? (4*g+j) : (16+4*g+j-4));
                    float w = 0.f;
                    if (kp < 70){
                        int row = (kp < 32) ? (38+kp) : (kp-32);
                        w = W1s[row*128 + 16*t + cl];
                    }
                    H.u[j] = (ushort_)bf16rne(w);
                }
                B1h[q][kt] = H.s;
            }
        }
        const int c = 16*wv + cl;
        pc1 = posk(c);
        bq[0] = b1s[c]; bq[1] = b1s[c+32]; bq[2] = b1s[c+64] + 1.0f; bq[3] = b1s[c+96];
        // redistributed cell rows: lower half-wave keeps r=0,1; upper takes mirror's r=2,3
        r1row0 = 4*(g&1) + ((ln >= 32) ? 2 : 0);
        r1row1 = r1row0 + 1;
    } else {
        #pragma unroll
        for (int t = 0; t < 5; ++t){
            #pragma unroll
            for (int kt = 0; kt < 2; ++kt){
                union { short8 s; ushort_ u[8]; } H;
                #pragma unroll
                for (int j = 0; j < 8; ++j){
                    int kp = kt*32 + ((j<4) ? (4*g+j) : (16+4*g+j-4));
                    float w = 0.f;
                    if (kp < 52) w = W2s[kp*80 + 16*t + cl];
                    H.u[j] = (ushort_)bf16rne(w);
                }
                B2h[t][kt] = H.s;
            }
            int col = 16*t + cl;
            bz2[t] = b2s[col] + ((col/20)==2 ? 1.f : 0.f);
        }
        zmask = (wv==2) ? (g==0) : (g==1);
        #pragma unroll
        for (int m = 0; m < 2; ++m){
            int e = ln + 64*m; c2v[m] = (e < 80);
            int es = c2v[m] ? e : 0;
            c2r[m] = 4*(wv-2) + es/20; c2c[m] = es%20; c2p[m] = posk(es%20);
        }
        const int sid = (wv-2)*64 + ln;
        int t1 = dir ? (TSTEPS-2) : 1;
        #pragma unroll
        for (int m = 0; m < 2; ++m){
            int e = sid + 128*m; stv[m] = (e < NB*19);
            int es = stv[m] ? e : 0;
            int b = es / 19, k = 2*(es % 19);
            stb[m] = b; stoff[m] = (k>>5)*32 + posk(k&31);
            stp[m] = x + ((size_t)(b0+b)*TSTEPS + t1)*INDIM + k;
            if (stv[m]){ xr[m] = *(const float2_*)stp[m]; stp[m] += dstep; }
        }
    }
    __syncthreads();

    // ================= phase body =================
    auto phase = [&](int p, int PX){
        const int PR = PX ^ 1;
        if (wv < 2){
            if (p < TSTEPS){
                short8 Ah[3], Al[3];
                Ah[0] = ldf(&inHh[PR][cl][g8]);      Al[0] = ldf(&inHl[PR][cl][g8]);
                Ah[1] = ldf(&inXh[PX][cl][g8]);      Al[1] = ldf(&inXl[PX][cl][g8]);
                Ah[2] = ldf(&inXh[PX][cl][32+g8]);   Al[2] = ldf(&inXl[PX][cl][32+g8]);
                // chain A (bias-init, depth 6): Ah x (Bh, Bl);  chain B (depth 3): Al x Bh
                float4_ ac[4], lh[4];
                #pragma unroll
                for (int q = 0; q < 4; ++q){
                    ac[q] = float4_{bq[q],bq[q],bq[q],bq[q]};
                    lh[q] = float4_{0,0,0,0};
                }
                #pragma unroll
                for (int kt = 0; kt < 3; ++kt){
                    #pragma unroll
                    for (int q = 0; q < 4; ++q) ac[q] = bmfma(Ah[kt], B1h[q][kt], ac[q]);
                }
                #pragma unroll
                for (int kt = 0; kt < 3; ++kt){
                    #pragma unroll
                    for (int q = 0; q < 4; ++q){
                        short8 bl = ldf(&W1Fl[wv + 2*q][cl][kt*32 + g8]);
                        ac[q] = bmfma(Ah[kt], bl, ac[q]);
                    }
                }
                #pragma unroll
                for (int kt = 0; kt < 3; ++kt){
                    #pragma unroll
                    for (int q = 0; q < 4; ++q) lh[q] = bmfma(Al[kt], B1h[q][kt], lh[q]);
                }
                float4_ a0 = ac[0]+lh[0], a1 = ac[1]+lh[1];
                float4_ a2 = ac[2]+lh[2], a3 = ac[3]+lh[3];
                // redistribute rows 2,3 to mirror lanes (upper half-wave held garbage rows)
                float s02=__shfl_xor(a0[2],32), s12=__shfl_xor(a1[2],32),
                      s22=__shfl_xor(a2[2],32), s32=__shfl_xor(a3[2],32);
                float s03=__shfl_xor(a0[3],32), s13=__shfl_xor(a1[3],32),
                      s23=__shfl_xor(a2[3],32), s33=__shfl_xor(a3[3],32);
                const bool up = (ln >= 32);
                float zi0 = up?s02:a0[0], zj0 = up?s12:a1[0], zf0 = up?s22:a2[0], zo0 = up?s32:a3[0];
                float zi1 = up?s03:a0[1], zj1 = up?s13:a1[1], zf1 = up?s23:a2[1], zo1 = up?s33:a3[1];
                c1a = fmaf(c1a, fsig(zf0), fsig(zi0)*ftanh(zj0));
                float h0 = ftanh(c1a) * fsig(zo0);
                c1b = fmaf(c1b, fsig(zf1), fsig(zi1)*ftanh(zj1));
                float h1 = ftanh(c1b) * fsig(zo1);
                unsigned p0 = cvt1(h0);
                inHh[PX][r1row0][pc1] = (ushort_)p0;
                inHl[PX][r1row0][pc1] = (ushort_)cvt1(h0 - __uint_as_float(p0<<16));
                unsigned p1 = cvt1(h1);
                inHh[PX][r1row1][pc1] = (ushort_)p1;
                inHl[PX][r1row1][pc1] = (ushort_)cvt1(h1 - __uint_as_float(p1<<16));
            }
        } else {
            if (p <= TSTEPS-2){
                #pragma unroll
                for (int m = 0; m < 2; ++m) if (stv[m]){
                    unsigned hp = cvt2(xr[m].x, xr[m].y);
                    *(unsigned*)&inXh[PR][stb[m]][stoff[m]] = hp;
                    float l0 = xr[m].x - __uint_as_float(hp<<16);
                    float l1 = xr[m].y - __uint_as_float(hp & 0xFFFF0000u);
                    *(unsigned*)&inXl[PR][stb[m]][stoff[m]] = cvt2(l0, l1);
                }
            }
            if (p <= TSTEPS-3){
                #pragma unroll
                for (int m = 0; m < 2; ++m) if (stv[m]){ xr[m] = *(const float2_*)stp[m]; stp[m] += dstep; }
            }
            if (p >= 1){
                short8 Ah0 = ldf(&inHh[PR][cl][g8]), Al0 = ldf(&inHl[PR][cl][g8]); // h1(p-1)
                short8 Gh  = ldf(&h2Ah[PR][cl][g8]), Gl  = ldf(&h2Al[PR][cl][g8]); // h2(p-2)
                float4_ ac[5], lh[5];
                #pragma unroll
                for (int t = 0; t < 5; ++t){
                    ac[t] = float4_{bz2[t],bz2[t],bz2[t],bz2[t]};
                    lh[t] = float4_{0,0,0,0};
                }
                #pragma unroll
                for (int t = 0; t < 5; ++t) ac[t] = bmfma(Ah0, B2h[t][0], ac[t]);
                #pragma unroll
                for (int t = 0; t < 5; ++t) ac[t] = bmfma(Gh,  B2h[t][1], ac[t]);
                #pragma unroll
                for (int t = 0; t < 5; ++t){
                    short8 bl0 = ldf(&W2Fl[t][cl][g8]);
                    ac[t] = bmfma(Ah0, bl0, ac[t]);
                }
                #pragma unroll
                for (int t = 0; t < 5; ++t){
                    short8 bl1 = ldf(&W2Fl[t][cl][32 + g8]);
                    ac[t] = bmfma(Gh, bl1, ac[t]);
                }
                #pragma unroll
                for (int t = 0; t < 5; ++t) lh[t] = bmfma(Al0, B2h[t][0], lh[t]);
                #pragma unroll
                for (int t = 0; t < 5; ++t) lh[t] = bmfma(Gl,  B2h[t][1], lh[t]);
                if (zmask){
                    #pragma unroll
                    for (int t = 0; t < 5; ++t){
                        float4_ a = ac[t] + lh[t];
                        #pragma unroll
                        for (int r = 0; r < 4; ++r) z2s[4*g + r][16*t + cl] = a[r];
                    }
                }
                #pragma unroll
                for (int m = 0; m < 2; ++m) if (c2v[m]){
                    const int rw = c2r[m], c = c2c[m];
                    float zi = z2s[rw][c],    zj = z2s[rw][c+20];
                    float zf = z2s[rw][c+40], zo = z2s[rw][c+60];
                    c2st[m] = fmaf(c2st[m], fsig(zf), fsig(zi)*ftanh(zj));
                    float h = ftanh(c2st[m]) * fsig(zo);
                    unsigned hp = cvt1(h);
                    h2Ah[PX][rw][c2p[m]] = (ushort_)hp;
                    h2Al[PX][rw][c2p[m]] = (ushort_)cvt1(h - __uint_as_float(hp<<16));
                    if (p == 1 || p == TSTEPS){
                        int off = (p == 1) ? (dir ? 60 : 0) : (dir ? 20 : 40);
                        featws[(size_t)(b0+rw)*80 + off + c] = h;
                    }
                }
            }
        }
        BAR();
    };

    for (int pp = 0; pp < TSTEPS; pp += 2){
        phase(pp, 0);
        phase(pp+1, 1);
    }
    phase(TSTEPS, 0);   // p=300: finish h2(299) + featws; L1 idle
}

__global__ __launch_bounds__(64) void fc_kernel(
    const float* __restrict__ featws,
    const float* __restrict__ Wfc1, const float* __restrict__ bfc1,
    const float* __restrict__ Wfc2, const float* __restrict__ bfc2,
    const float* __restrict__ Wfc3, const float* __restrict__ bfc3,
    float* __restrict__ out)
{
    __shared__ float f[80];
    __shared__ float h1b[80];
    __shared__ float h2b[20];
    const int b = blockIdx.x;
    const int lane = threadIdx.x;

    for (int i = lane; i < 80; i += 64) f[i] = featws[(size_t)b*80 + i];
    __syncthreads();
    for (int j = lane; j < 80; j += 64){
        float s = bfc1[j];
        #pragma unroll 8
        for (int k = 0; k < 80; ++k) s += f[k]*Wfc1[k*80 + j];
        h1b[j] = ftanh(s);
    }
    __syncthreads();
    if (lane < 20){
        float s = bfc2[lane];
        #pragma unroll 8
        for (int k = 0; k < 80; ++k) s += h1b[k]*Wfc2[k*20 + lane];
        h2b[lane] = ftanh(s);
    }
    __syncthreads();
    if (lane < 3){
        float s = bfc3[lane];
        #pragma unroll
        for (int k = 0; k < 20; ++k) s += h2b[k]*Wfc3[k*3 + lane];
        out[(size_t)b*3 + lane] = s;
    }
}

extern "C" void kernel_launch(void* const* d_in, const int* in_sizes, int n_in,
                              void* d_out, int out_size, void* d_ws, size_t ws_size,
                              hipStream_t stream) {
    const float* x    = (const float*)d_in[0];
    const float* Wf1  = (const float*)d_in[1];
    const float* bf1  = (const float*)d_in[2];
    const float* Wf2  = (const float*)d_in[3];
    const float* bf2  = (const float*)d_in[4];
    const float* Wb1  = (const float*)d_in[5];
    const float* bb1  = (const float*)d_in[6];
    const float* Wb2  = (const float*)d_in[7];
    const float* bb2  = (const float*)d_in[8];
    const float* Wfc1 = (const float*)d_in[9];
    const float* bfc1 = (const float*)d_in[10];
    const float* Wfc2 = (const float*)d_in[11];
    const float* bfc2 = (const float*)d_in[12];
    const float* Wfc3 = (const float*)d_in[13];
    const float* bfc3 = (const float*)d_in[14];

    float* feat = (float*)d_ws; // 2048*80*4 = 655360 B

    rnn_kernel<<<dim3(2048/NB, 2), 256, 0, stream>>>(
        x, Wf1, bf1, Wf2, bf2, Wb1, bb1, Wb2, bb2, feat);
    fc_kernel<<<2048, 64, 0, stream>>>(
        feat, Wfc1, bfc1, Wfc2, bfc2, Wfc3, bfc3, (float*)d_out);
}

// Round 14
// 346.806 us; speedup vs baseline: 2.5429x; 1.0079x over previous
//
#include <hip/hip_runtime.h>
#include <hip/hip_bf16.h>

#define TSTEPS 300
#define INDIM  38
#define NB     8

typedef __attribute__((ext_vector_type(4))) float    float4_;
typedef __attribute__((ext_vector_type(2))) float    float2_;
typedef __attribute__((ext_vector_type(8))) short    short8;
typedef unsigned short ushort_;

__device__ __forceinline__ float frcp(float x){ return __builtin_amdgcn_rcpf(x); }
__device__ __forceinline__ float fexp2(float x){ float r; asm("v_exp_f32 %0, %1" : "=v"(r) : "v"(x)); return r; }
__device__ __forceinline__ float fsig(float x){ return frcp(1.0f + fexp2(-1.44269504f*x)); }
__device__ __forceinline__ float ftanh(float x){ return 1.0f - 2.0f*frcp(1.0f + fexp2(2.88539008f*x)); }
__device__ __forceinline__ unsigned bf16rne(float f){
    unsigned u = __float_as_uint(f);
    return (u + 0x7FFFu + ((u>>16)&1u)) >> 16;
}
// single f32 -> bf16 in low 16 bits (1 inst)
__device__ __forceinline__ unsigned cvt1(float f){
    unsigned r; asm("v_cvt_pk_bf16_f32 %0,%1,%1" : "=v"(r) : "v"(f)); return r;
}
__device__ __forceinline__ unsigned cvt2(float a, float b){
    unsigned r; asm("v_cvt_pk_bf16_f32 %0,%1,%2" : "=v"(r) : "v"(a), "v"(b)); return r;
}
// mirror across the 32-lane halves; ONLY the upper-half lanes' result is used
// (callers select). permlane32_swap: r[0][l] = l<32 ? x[l] : x[l-32].
#if __has_builtin(__builtin_amdgcn_permlane32_swap)
__device__ __forceinline__ float mir32(float x){
    auto r = __builtin_amdgcn_permlane32_swap(__float_as_uint(x), __float_as_uint(x), false, false);
    return __uint_as_float(r[0]);
}
#else
__device__ __forceinline__ float mir32(float x){ return __shfl_xor(x, 32); }
#endif
// frag-native position of k-element rel (0..31) within a 32-k tile
__device__ __forceinline__ int posk(int rel){ return 8*((rel&15)>>2) + (rel&3) + 4*(rel>>4); }
__device__ __forceinline__ short8 ldf(const ushort_* p){ return *(const short8*)p; }
__device__ __forceinline__ float4_ bmfma(short8 a, short8 b, float4_ c){
    return __builtin_amdgcn_mfma_f32_16x16x32_bf16(a, b, c, 0, 0, 0);
}
// raw barrier: drains LDS only; global loads stay in flight
#define BAR() do{ asm volatile("s_waitcnt lgkmcnt(0)" ::: "memory"); \
                  __builtin_amdgcn_s_barrier(); \
                  asm volatile("" ::: "memory"); }while(0)

// r13 skeleton (349us): 256 thr = 4 waves, NB=8, grid (256,2)=512 blocks = 2/CU.
// HI weight planes in registers (L1 48, L2 40 VGPR); LO planes streamed from LDS.
// r14 deltas: (a) s_setprio(1) around MFMA clusters (T5; role-split + 2-block
// phase diversity now present); (b) permlane32_swap for the cell1 mirror
// (off the LDS pipe); (c) L2: A-frag ds_reads issued before x staging.
__global__ __launch_bounds__(256,2) void rnn_kernel(
    const float* __restrict__ x,
    const float* __restrict__ Wf1, const float* __restrict__ bf1,
    const float* __restrict__ Wf2, const float* __restrict__ bf2,
    const float* __restrict__ Wb1, const float* __restrict__ bb1,
    const float* __restrict__ Wb2, const float* __restrict__ bb2,
    float* __restrict__ featws)
{
    __shared__ __attribute__((aligned(16))) ushort_ W1Fl[8][16][104];   // lo plane, frag-native
    __shared__ __attribute__((aligned(16))) ushort_ W2Fl[5][16][72];    // lo plane
    __shared__ __attribute__((aligned(16))) ushort_ inHh[2][16][40],  inHl[2][16][40];
    __shared__ __attribute__((aligned(16))) ushort_ inXh[2][16][104], inXl[2][16][104];
    __shared__ __attribute__((aligned(16))) ushort_ h2Ah[2][16][40],  h2Al[2][16][40];
    __shared__ float z2s[8][84];

    const int tid = threadIdx.x;
    const int dir = blockIdx.y;
    const int b0  = blockIdx.x * NB;

    const float* W1s = dir ? Wb1 : Wf1;
    const float* b1s = dir ? bb1 : bf1;
    const float* W2s = dir ? Wb2 : Wf2;
    const float* b2s = dir ? bb2 : bf2;

    // ---------------- zero-init (pads + rows 8..15 + h(-1)=0) ----------------
    for (int i = tid; i < 8*16*104; i += 256) ((ushort_*)W1Fl)[i] = 0;
    for (int i = tid; i < 5*16*72;  i += 256) ((ushort_*)W2Fl)[i] = 0;
    for (int i = tid; i < 2*16*40;  i += 256){ ((ushort_*)inHh)[i]=0; ((ushort_*)inHl)[i]=0;
                                               ((ushort_*)h2Ah)[i]=0; ((ushort_*)h2Al)[i]=0; }
    for (int i = tid; i < 2*16*104; i += 256){ ((ushort_*)inXh)[i]=0; ((ushort_*)inXl)[i]=0; }
    __syncthreads();
    // ---------------- stage weight LO planes (frag-native) ----------------
    for (int idx = tid; idx < 70*128; idx += 256){
        int k = idx >> 7, c = idx & 127;
        int kp = (k < INDIM) ? (k + 32) : (k - INDIM);   // [h1(0..31) | x(32..69)]
        float w = W1s[idx];
        unsigned hu = bf16rne(w);
        W1Fl[c>>4][c&15][(kp>>5)*32 + posk(kp&31)] =
            (ushort_)bf16rne(w - __uint_as_float(hu<<16));
    }
    for (int idx = tid; idx < 52*80; idx += 256){
        int k = idx / 80, c = idx % 80;                  // [h1(0..31) | h2(32..51)]
        float w = W2s[idx];
        unsigned hu = bf16rne(w);
        W2Fl[c/16][c&15][(k>>5)*32 + posk(k&31)] =
            (ushort_)bf16rne(w - __uint_as_float(hu<<16));
    }
    // ---------------- x(0) -> inX[0] rows 0..7 ----------------
    for (int idx = tid; idx < NB*INDIM; idx += 256){
        int t0 = dir ? (TSTEPS-1) : 0;
        int b = idx / INDIM, k = idx % INDIM;
        int off = (k>>5)*32 + posk(k&31);
        float w = x[((size_t)(b0+b)*TSTEPS + t0)*INDIM + k];
        unsigned hu = bf16rne(w);
        inXh[0][b][off] = (ushort_)hu;
        inXl[0][b][off] = (ushort_)bf16rne(w - __uint_as_float(hu<<16));
    }

    const int wv = tid >> 6;
    const int ln = tid & 63;
    const int g  = ln >> 4;
    const int cl = ln & 15;
    const int g8 = 8*g;
    const int dstep = dir ? -INDIM : INDIM;

    // ================= role state =================
    short8 B1h[4][3];                       // L1 hi planes (48 VGPR)
    float bq[4] = {0,0,0,0};
    int pc1 = 0, r1row0 = 0, r1row1 = 0;
    float c1a = 0.f, c1b = 0.f;
    short8 B2h[5][2];                       // L2 hi planes (40 VGPR)
    float bz2[5] = {0,0,0,0,0};
    bool zmask = false;
    bool c2v[2] = {false,false}; int c2r[2]={0,0}, c2c[2]={0,0}, c2p[2]={0,0};
    float c2st[2] = {0.f,0.f};
    bool stv[2] = {false,false}; int stb[2]={0,0}, stoff[2]={0,0};
    const float* stp[2] = {x,x}; float2_ xr[2] = {{0,0},{0,0}};

    if (wv < 2){
        #pragma unroll
        for (int q = 0; q < 4; ++q){
            const int t = wv + 2*q;
            #pragma unroll
            for (int kt = 0; kt < 3; ++kt){
                union { short8 s; ushort_ u[8]; } H;
                #pragma unroll
                for (int j = 0; j < 8; ++j){
                    int kp = kt*32 + ((j<4) ? (4*g+j) : (16+4*g+j-4));
                    float w = 0.f;
                    if (kp < 70){
                        int row = (kp < 32) ? (38+kp) : (kp-32);
                        w = W1s[row*128 + 16*t + cl];
                    }
                    H.u[j] = (ushort_)bf16rne(w);
                }
                B1h[q][kt] = H.s;
            }
        }
        const int c = 16*wv + cl;
        pc1 = posk(c);
        bq[0] = b1s[c]; bq[1] = b1s[c+32]; bq[2] = b1s[c+64] + 1.0f; bq[3] = b1s[c+96];
        // redistributed cell rows: lower half-wave keeps r=0,1; upper takes mirror's r=2,3
        r1row0 = 4*(g&1) + ((ln >= 32) ? 2 : 0);
        r1row1 = r1row0 + 1;
    } else {
        #pragma unroll
        for (int t = 0; t < 5; ++t){
            #pragma unroll
            for (int kt = 0; kt < 2; ++kt){
                union { short8 s; ushort_ u[8]; } H;
                #pragma unroll
                for (int j = 0; j < 8; ++j){
                    int kp = kt*32 + ((j<4) ? (4*g+j) : (16+4*g+j-4));
                    float w = 0.f;
                    if (kp < 52) w = W2s[kp*80 + 16*t + cl];
                    H.u[j] = (ushort_)bf16rne(w);
                }
                B2h[t][kt] = H.s;
            }
            int col = 16*t + cl;
            bz2[t] = b2s[col] + ((col/20)==2 ? 1.f : 0.f);
        }
        zmask = (wv==2) ? (g==0) : (g==1);
        #pragma unroll
        for (int m = 0; m < 2; ++m){
            int e = ln + 64*m; c2v[m] = (e < 80);
            int es = c2v[m] ? e : 0;
            c2r[m] = 4*(wv-2) + es/20; c2c[m] = es%20; c2p[m] = posk(es%20);
        }
        const int sid = (wv-2)*64 + ln;
        int t1 = dir ? (TSTEPS-2) : 1;
        #pragma unroll
        for (int m = 0; m < 2; ++m){
            int e = sid + 128*m; stv[m] = (e < NB*19);
            int es = stv[m] ? e : 0;
            int b = es / 19, k = 2*(es % 19);
            stb[m] = b; stoff[m] = (k>>5)*32 + posk(k&31);
            stp[m] = x + ((size_t)(b0+b)*TSTEPS + t1)*INDIM + k;
            if (stv[m]){ xr[m] = *(const float2_*)stp[m]; stp[m] += dstep; }
        }
    }
    __syncthreads();

    // ================= phase body =================
    auto phase = [&](int p, int PX){
        const int PR = PX ^ 1;
        if (wv < 2){
            if (p < TSTEPS){
                short8 Ah[3], Al[3];
                Ah[0] = ldf(&inHh[PR][cl][g8]);      Al[0] = ldf(&inHl[PR][cl][g8]);
                Ah[1] = ldf(&inXh[PX][cl][g8]);      Al[1] = ldf(&inXl[PX][cl][g8]);
                Ah[2] = ldf(&inXh[PX][cl][32+g8]);   Al[2] = ldf(&inXl[PX][cl][32+g8]);
                // chain A (bias-init, depth 6): Ah x (Bh, Bl);  chain B (depth 3): Al x Bh
                float4_ ac[4], lh[4];
                #pragma unroll
                for (int q = 0; q < 4; ++q){
                    ac[q] = float4_{bq[q],bq[q],bq[q],bq[q]};
                    lh[q] = float4_{0,0,0,0};
                }
                __builtin_amdgcn_s_setprio(1);
                #pragma unroll
                for (int kt = 0; kt < 3; ++kt){
                    #pragma unroll
                    for (int q = 0; q < 4; ++q) ac[q] = bmfma(Ah[kt], B1h[q][kt], ac[q]);
                }
                #pragma unroll
                for (int kt = 0; kt < 3; ++kt){
                    #pragma unroll
                    for (int q = 0; q < 4; ++q){
                        short8 bl = ldf(&W1Fl[wv + 2*q][cl][kt*32 + g8]);
                        ac[q] = bmfma(Ah[kt], bl, ac[q]);
                    }
                }
                #pragma unroll
                for (int kt = 0; kt < 3; ++kt){
                    #pragma unroll
                    for (int q = 0; q < 4; ++q) lh[q] = bmfma(Al[kt], B1h[q][kt], lh[q]);
                }
                __builtin_amdgcn_s_setprio(0);
                float4_ a0 = ac[0]+lh[0], a1 = ac[1]+lh[1];
                float4_ a2 = ac[2]+lh[2], a3 = ac[3]+lh[3];
                // rows 2,3 mirrored to upper half-wave lanes (which held garbage rows)
                float s02=mir32(a0[2]), s12=mir32(a1[2]), s22=mir32(a2[2]), s32=mir32(a3[2]);
                float s03=mir32(a0[3]), s13=mir32(a1[3]), s23=mir32(a2[3]), s33=mir32(a3[3]);
                const bool up = (ln >= 32);
                float zi0 = up?s02:a0[0], zj0 = up?s12:a1[0], zf0 = up?s22:a2[0], zo0 = up?s32:a3[0];
                float zi1 = up?s03:a0[1], zj1 = up?s13:a1[1], zf1 = up?s23:a2[1], zo1 = up?s33:a3[1];
                c1a = fmaf(c1a, fsig(zf0), fsig(zi0)*ftanh(zj0));
                float h0 = ftanh(c1a) * fsig(zo0);
                c1b = fmaf(c1b, fsig(zf1), fsig(zi1)*ftanh(zj1));
                float h1 = ftanh(c1b) * fsig(zo1);
                unsigned p0 = cvt1(h0);
                inHh[PX][r1row0][pc1] = (ushort_)p0;
                inHl[PX][r1row0][pc1] = (ushort_)cvt1(h0 - __uint_as_float(p0<<16));
                unsigned p1 = cvt1(h1);
                inHh[PX][r1row1][pc1] = (ushort_)p1;
                inHl[PX][r1row1][pc1] = (ushort_)cvt1(h1 - __uint_as_float(p1<<16));
            }
        } else {
            // A-frag reads FIRST (latency hides under staging VALU below)
            short8 Ah0, Al0, Gh, Gl;
            if (p >= 1){
                Ah0 = ldf(&inHh[PR][cl][g8]); Al0 = ldf(&inHl[PR][cl][g8]); // h1(p-1)
                Gh  = ldf(&h2Ah[PR][cl][g8]); Gl  = ldf(&h2Al[PR][cl][g8]); // h2(p-2)
            }
            if (p <= TSTEPS-2){
                #pragma unroll
                for (int m = 0; m < 2; ++m) if (stv[m]){
                    unsigned hp = cvt2(xr[m].x, xr[m].y);
                    *(unsigned*)&inXh[PR][stb[m]][stoff[m]] = hp;
                    float l0 = xr[m].x - __uint_as_float(hp<<16);
                    float l1 = xr[m].y - __uint_as_float(hp & 0xFFFF0000u);
                    *(unsigned*)&inXl[PR][stb[m]][stoff[m]] = cvt2(l0, l1);
                }
            }
            if (p <= TSTEPS-3){
                #pragma unroll
                for (int m = 0; m < 2; ++m) if (stv[m]){ xr[m] = *(const float2_*)stp[m]; stp[m] += dstep; }
            }
            if (p >= 1){
                float4_ ac[5], lh[5];
                #pragma unroll
                for (int t = 0; t < 5; ++t){
                    ac[t] = float4_{bz2[t],bz2[t],bz2[t],bz2[t]};
                    lh[t] = float4_{0,0,0,0};
                }
                __builtin_amdgcn_s_setprio(1);
                #pragma unroll
                for (int t = 0; t < 5; ++t) ac[t] = bmfma(Ah0, B2h[t][0], ac[t]);
                #pragma unroll
                for (int t = 0; t < 5; ++t) ac[t] = bmfma(Gh,  B2h[t][1], ac[t]);
                #pragma unroll
                for (int t = 0; t < 5; ++t){
                    short8 bl0 = ldf(&W2Fl[t][cl][g8]);
                    ac[t] = bmfma(Ah0, bl0, ac[t]);
                }
                #pragma unroll
                for (int t = 0; t < 5; ++t){
                    short8 bl1 = ldf(&W2Fl[t][cl][32 + g8]);
                    ac[t] = bmfma(Gh, bl1, ac[t]);
                }
                #pragma unroll
                for (int t = 0; t < 5; ++t) lh[t] = bmfma(Al0, B2h[t][0], lh[t]);
                #pragma unroll
                for (int t = 0; t < 5; ++t) lh[t] = bmfma(Gl,  B2h[t][1], lh[t]);
                __builtin_amdgcn_s_setprio(0);
                if (zmask){
                    #pragma unroll
                    for (int t = 0; t < 5; ++t){
                        float4_ a = ac[t] + lh[t];
                        #pragma unroll
                        for (int r = 0; r < 4; ++r) z2s[4*g + r][16*t + cl] = a[r];
                    }
                }
                #pragma unroll
                for (int m = 0; m < 2; ++m) if (c2v[m]){
                    const int rw = c2r[m], c = c2c[m];
                    float zi = z2s[rw][c],    zj = z2s[rw][c+20];
                    float zf = z2s[rw][c+40], zo = z2s[rw][c+60];
                    c2st[m] = fmaf(c2st[m], fsig(zf), fsig(zi)*ftanh(zj));
                    float h = ftanh(c2st[m]) * fsig(zo);
                    unsigned hp = cvt1(h);
                    h2Ah[PX][rw][c2p[m]] = (ushort_)hp;
                    h2Al[PX][rw][c2p[m]] = (ushort_)cvt1(h - __uint_as_float(hp<<16));
                    if (p == 1 || p == TSTEPS){
                        int off = (p == 1) ? (dir ? 60 : 0) : (dir ? 20 : 40);
                        featws[(size_t)(b0+rw)*80 + off + c] = h;
                    }
                }
            }
        }
    };

    for (int pp = 0; pp < TSTEPS; pp += 2){
        phase(pp, 0);   BAR();
        phase(pp+1, 1); BAR();
    }
    phase(TSTEPS, 0);   // p=300: finish h2(299) + featws; no barrier needed (kernel ends)
}

__global__ __launch_bounds__(64) void fc_kernel(
    const float* __restrict__ featws,
    const float* __restrict__ Wfc1, const float* __restrict__ bfc1,
    const float* __restrict__ Wfc2, const float* __restrict__ bfc2,
    const float* __restrict__ Wfc3, const float* __restrict__ bfc3,
    float* __restrict__ out)
{
    __shared__ float f[80];
    __shared__ float h1b[80];
    __shared__ float h2b[20];
    const int b = blockIdx.x;
    const int lane = threadIdx.x;

    for (int i = lane; i < 80; i += 64) f[i] = featws[(size_t)b*80 + i];
    __syncthreads();
    for (int j = lane; j < 80; j += 64){
        float s = bfc1[j];
        #pragma unroll 8
        for (int k = 0; k < 80; ++k) s += f[k]*Wfc1[k*80 + j];
        h1b[j] = ftanh(s);
    }
    __syncthreads();
    if (lane < 20){
        float s = bfc2[lane];
        #pragma unroll 8
        for (int k = 0; k < 80; ++k) s += h1b[k]*Wfc2[k*20 + lane];
        h2b[lane] = ftanh(s);
    }
    __syncthreads();
    if (lane < 3){
        float s = bfc3[lane];
        #pragma unroll
        for (int k = 0; k < 20; ++k) s += h2b[k]*Wfc3[k*3 + lane];
        out[(size_t)b*3 + lane] = s;
    }
}

extern "C" void kernel_launch(void* const* d_in, const int* in_sizes, int n_in,
                              void* d_out, int out_size, void* d_ws, size_t ws_size,
                              hipStream_t stream) {
    const float* x    = (const float*)d_in[0];
    const float* Wf1  = (const float*)d_in[1];
    const float* bf1  = (const float*)d_in[2];
    const float* Wf2  = (const float*)d_in[3];
    const float* bf2  = (const float*)d_in[4];
    const float* Wb1  = (const float*)d_in[5];
    const float* bb1  = (const float*)d_in[6];
    const float* Wb2  = (const float*)d_in[7];
    const float* bb2  = (const float*)d_in[8];
    const float* Wfc1 = (const float*)d_in[9];
    const float* bfc1 = (const float*)d_in[10];
    const float* Wfc2 = (const float*)d_in[11];
    const float* bfc2 = (const float*)d_in[12];
    const float* Wfc3 = (const float*)d_in[13];
    const float* bfc3 = (const float*)d_in[14];

    float* feat = (float*)d_ws; // 2048*80*4 = 655360 B

    rnn_kernel<<<dim3(2048/NB, 2), 256, 0, stream>>>(
        x, Wf1, bf1, Wf2, bf2, Wb1, bb1, Wb2, bb2, feat);
    fc_kernel<<<2048, 64, 0, stream>>>(
        feat, Wfc1, bfc1, Wfc2, bfc2, Wfc3, bfc3, (float*)d_out);
}